// Round 21
// baseline (135.528 us; speedup 1.0000x reference)
//
#include <hip/hip_runtime.h>
#include <hip/hip_bf16.h>

typedef __bf16 bf16x8 __attribute__((ext_vector_type(8)));
typedef float  f32x4  __attribute__((ext_vector_type(4)));

#define T_LEN 4096
#define QBLK  128
#define NIT   32          // 32 superblocks x 128 s

__device__ __forceinline__ int swz(int row, int colByte) {
    return row * 128 + (colByte ^ (((row ^ (row >> 2)) & 7) << 4));
}
__device__ __forceinline__ int swzM(int row, int colByte) {   // merge buf [c][t] f32
    return row * 128 + (colByte ^ ((row & 7) << 4));
}
__device__ __forceinline__ int swzO(int row, int colByte) {   // epilogue f32 [c][128t]
    return row * 512 + (colByte ^ ((row & 7) << 5));
}

// Q pre-scale: 1/8 (QK scale) x log2(e); no-max exp2 softmax (r9-verified).
#define QSCALE 0.18033688011112042f

#if __has_builtin(__builtin_amdgcn_exp2f)
#define EXP2(x) __builtin_amdgcn_exp2f(x)
#else
__device__ __forceinline__ float EXP2(float x) {
    float r; asm("v_exp_f32 %0, %1" : "=v"(r) : "v"(x)); return r;
}
#endif

__device__ __forceinline__ void glds16(const void* g, void* l) {
    __builtin_amdgcn_global_load_lds(
        (const __attribute__((address_space(1))) void*)g,
        (__attribute__((address_space(3))) void*)l, 16, 0, 0);
}

// ---------------- prepass ---------------------------------------------------
// K -> swizzled LDS images (r18-verified glds format).
// V -> per-wave-fragment 1KB chunks (r20-verified register-stream format).
__global__ __launch_bounds__(256)
void qkv_prepass(const float* __restrict__ qkv, char* __restrict__ kpan,
                 char* __restrict__ vpan) {
    const int tile = blockIdx.x;    // 0..63
    const int bh   = blockIdx.y;    // 0..15
    const float* kp = qkv + ((size_t)bh * 192 + 64)  * T_LEN + tile * 64;
    const float* vp = qkv + ((size_t)bh * 192 + 128) * T_LEN + tile * 64;
    char* kout = kpan + (size_t)(bh * 64 + tile) * 8192;
    char* vout = vpan + (size_t)(bh * 64 + tile) * 8192;

    const int t = threadIdx.x;
    // ---- K: swizzled [64 s][64 c] bf16 image (r18 layout) ----
    {
        const int s  = t & 63;
        const int o4 = t >> 6;          // 0..3
        #pragma unroll
        for (int oo = 0; oo < 2; ++oo) {
            const int oct = o4 + oo * 4;                 // c-octet 0..7
            bf16x8 v;
            #pragma unroll
            for (int j = 0; j < 8; ++j)
                v[j] = (__bf16)kp[(size_t)(oct * 8 + j) * T_LEN + s];
            *(bf16x8*)(kout + swz(s, oct * 16)) = v;
        }
    }
    // ---- V: fragment chunks (r20 layout): chunk half*4+n, lane(g,i)*16B ----
    {
        const int c = t & 63;           // = n*16 + i
        #pragma unroll
        for (int lp = 0; lp < 2; ++lp) {
            const int hg = (t >> 6) + lp * 4;            // 0..7
            const int hf = hg >> 2, gg = hg & 3;
            float4 f0 = *(const float4*)(vp + (size_t)c * T_LEN + hf * 32 + gg * 4);
            float4 f1 = *(const float4*)(vp + (size_t)c * T_LEN + hf * 32 + 16 + gg * 4);
            bf16x8 v;
            v[0] = (__bf16)f0.x; v[1] = (__bf16)f0.y;
            v[2] = (__bf16)f0.z; v[3] = (__bf16)f0.w;
            v[4] = (__bf16)f1.x; v[5] = (__bf16)f1.y;
            v[6] = (__bf16)f1.z; v[7] = (__bf16)f1.w;
            const int chunk   = hf * 4 + (c >> 4);
            const int lanepos = gg * 16 + (c & 15);
            *(bf16x8*)(vout + chunk * 1024 + lanepos * 16) = v;
        }
    }
}

// ---------------- main: K-LDS / V-register hybrid ---------------------------
// r18 champion structure (superblock dbuf + phase grouping + setprio), but V
// streams from L2 panels into vf[2][4] at loop top (consumed after S+exp ≈
// 400+ cyc — latency hidden, nothing fresh in flight at the barrier). LDS
// pipe traffic halves; LDS 80K -> 48K.
// LDS map: [0,16K) Qs (dead after qreg; lbase reuse) |
//          [16K,48K) Ks dbuf 2x16K (mbase reuse post-loop).
// Epilogue Obuf reuses [0,32K) after merge (r18-verified barrier flow).
__global__ __launch_bounds__(512, 4)
void qkv_attn_hyb(const float* __restrict__ qkv, float* __restrict__ out,
                  const char* __restrict__ kpan, const char* __restrict__ vpan) {
    __shared__ __align__(16) char lds[49152];

    const int fid   = (blockIdx.x & 7) * 64 + (blockIdx.x >> 3);   // T1 swizzle
    const int bh    = fid >> 5;
    const int ttile = fid & 31;
    const float* qp = qkv + (size_t)bh * 192 * T_LEN;
    const char* kpb = kpan + (size_t)bh * 64 * 8192;
    const int t0 = ttile * QBLK;

    const int tid  = threadIdx.x;
    const int wave = tid >> 6, lane = tid & 63;
    const int g = lane >> 4, i = lane & 15;
    const int tg = wave >> 1, half = wave & 1;   // t-group (32 rows), s-half

    // V fragment base (r20-verified): 4KB per half per tile, lane-contiguous
    const char* vbase = vpan + (size_t)bh * 64 * 8192 + half * 4096 + lane * 16;

    // ---- prologue: glds K superblock 0; vf <- tiles 0,1 ----
    glds16(kpb + tid * 16,        lds + 16384 + wave * 1024);
    glds16(kpb + 8192 + tid * 16, lds + 16384 + 8192 + wave * 1024);
    bf16x8 vf[2][4];
    #pragma unroll
    for (int q = 0; q < 4; ++q) {
        vf[0][q] = *(const bf16x8*)(vbase + q * 1024);
        vf[1][q] = *(const bf16x8*)(vbase + 8192 + q * 1024);
    }

    // ---- stage Q^T x QSCALE : [128 t][64 c] ----
    {
        const int tq  = (tid & 31) * 4;
        const int cp8 = tid >> 5;
        #pragma unroll
        for (int hh = 0; hh < 2; ++hh) {
            const int cpair = cp8 + hh * 16;
            const float* base = qp + (size_t)(cpair * 2) * T_LEN + t0 + tq;
            float4 lo = *(const float4*)(base);
            float4 hi = *(const float4*)(base + T_LEN);
            __bf16 v0, v1;
            v0 = (__bf16)(lo.x * QSCALE); v1 = (__bf16)(hi.x * QSCALE);
            *(__bf16*)(lds + swz(tq + 0, cpair * 4)) = v0;
            *(__bf16*)(lds + swz(tq + 0, cpair * 4) + 2) = v1;
            v0 = (__bf16)(lo.y * QSCALE); v1 = (__bf16)(hi.y * QSCALE);
            *(__bf16*)(lds + swz(tq + 1, cpair * 4)) = v0;
            *(__bf16*)(lds + swz(tq + 1, cpair * 4) + 2) = v1;
            v0 = (__bf16)(lo.z * QSCALE); v1 = (__bf16)(hi.z * QSCALE);
            *(__bf16*)(lds + swz(tq + 2, cpair * 4)) = v0;
            *(__bf16*)(lds + swz(tq + 2, cpair * 4) + 2) = v1;
            v0 = (__bf16)(lo.w * QSCALE); v1 = (__bf16)(hi.w * QSCALE);
            *(__bf16*)(lds + swz(tq + 3, cpair * 4)) = v0;
            *(__bf16*)(lds + swz(tq + 3, cpair * 4) + 2) = v1;
        }
    }
    __syncthreads();   // Q staged + K superblock 0 drained
    bf16x8 qreg[2][2];   // [t-half][kk], loop-invariant; Qs LDS dead after
    #pragma unroll
    for (int h = 0; h < 2; ++h)
        #pragma unroll
        for (int kk = 0; kk < 2; ++kk)
            qreg[h][kk] = *(const bf16x8*)(lds + swz(tg * 32 + h * 16 + i, kk * 64 + g * 16));

    f32x4 oacc[2][4];
    #pragma unroll
    for (int h = 0; h < 2; ++h)
        #pragma unroll
        for (int n = 0; n < 4; ++n) oacc[h][n] = (f32x4){0.f, 0.f, 0.f, 0.f};
    float l0 = 0.f, l1 = 0.f;   // lane-local partials; shfl-reduced post-loop

    for (int it = 0; it < NIT; ++it) {
        // ---- loop-top refills: vf <- this superblock's tiles (it>0); ----
        // ---- K glds <- next superblock. Gap to use >= S+exp phases. ----
        if (it > 0) {
            const char* vn = vbase + (size_t)(2 * it) * 8192;
            #pragma unroll
            for (int q = 0; q < 4; ++q) {
                vf[0][q] = *(const bf16x8*)(vn + q * 1024);
                vf[1][q] = *(const bf16x8*)(vn + 8192 + q * 1024);
            }
        }
        if (it + 1 < NIT) {
            const size_t off = (size_t)(2 * it + 2) * 8192;
            const int b = (it + 1) & 1;
            glds16(kpb + off + tid * 16,        lds + 16384 + b * 16384 + wave * 1024);
            glds16(kpb + off + 8192 + tid * 16, lds + 16384 + b * 16384 + 8192 + wave * 1024);
        }
        char* KsB = lds + 16384 + (it & 1) * 16384;

        // ---- S phase: both tiles' K-frags + 32 S-MFMAs ----
        f32x4 sacc[2][2][2];   // [ta][t-half][mt]
        #pragma unroll
        for (int ta = 0; ta < 2; ++ta)
            #pragma unroll
            for (int h = 0; h < 2; ++h)
                #pragma unroll
                for (int mt = 0; mt < 2; ++mt) sacc[ta][h][mt] = (f32x4){0.f, 0.f, 0.f, 0.f};
        __builtin_amdgcn_s_setprio(1);
        #pragma unroll
        for (int ta = 0; ta < 2; ++ta)
            #pragma unroll
            for (int kk = 0; kk < 2; ++kk)
                #pragma unroll
                for (int mt = 0; mt < 2; ++mt) {
                    bf16x8 kf = *(const bf16x8*)(KsB + ta * 8192 + swz(half * 32 + mt * 16 + i, kk * 64 + g * 16));
                    sacc[ta][0][mt] = __builtin_amdgcn_mfma_f32_16x16x32_bf16(kf, qreg[0][kk], sacc[ta][0][mt], 0, 0, 0);
                    sacc[ta][1][mt] = __builtin_amdgcn_mfma_f32_16x16x32_bf16(kf, qreg[1][kk], sacc[ta][1][mt], 0, 0, 0);
                }
        __builtin_amdgcn_s_setprio(0);

        // ---- exp phase: 32 exp2 + packs ----
        bf16x8 pa[2][2];   // [ta][t-half]
        #pragma unroll
        for (int ta = 0; ta < 2; ++ta)
            #pragma unroll
            for (int r = 0; r < 4; ++r) {
                float a0 = EXP2(sacc[ta][0][0][r]);
                float a1 = EXP2(sacc[ta][0][1][r]);
                l0 += a0 + a1;
                pa[ta][0][r] = (__bf16)a0; pa[ta][0][4 + r] = (__bf16)a1;
                float b0 = EXP2(sacc[ta][1][0][r]);
                float b1 = EXP2(sacc[ta][1][1][r]);
                l1 += b0 + b1;
                pa[ta][1][r] = (__bf16)b0; pa[ta][1][4 + r] = (__bf16)b1;
            }

        // ---- PV phase: vf registers + 32 PV-MFMAs ----
        __builtin_amdgcn_s_setprio(1);
        #pragma unroll
        for (int ta = 0; ta < 2; ++ta)
            #pragma unroll
            for (int n = 0; n < 4; ++n) {
                oacc[0][n] = __builtin_amdgcn_mfma_f32_16x16x32_bf16(pa[ta][0], vf[ta][n], oacc[0][n], 0, 0, 0);
                oacc[1][n] = __builtin_amdgcn_mfma_f32_16x16x32_bf16(pa[ta][1], vf[ta][n], oacc[1][n], 0, 0, 0);
            }
        __builtin_amdgcn_s_setprio(0);
        __syncthreads();   // next K bufs ready (K glds landed); reads fenced
    }
    l0 += __shfl_xor(l0, 16); l0 += __shfl_xor(l0, 32);
    l1 += __shfl_xor(l1, 16); l1 += __shfl_xor(l1, 32);

    // ---- merge s-halves (additive), then epilogue ----
    char* mbase = lds + 16384 + tg * 8192;   // [64 c][32 t] f32, swzM (K dbuf dead)
    float* lbase = (float*)(lds);            // Qs region dead
    if (half == 1) {
        #pragma unroll
        for (int h = 0; h < 2; ++h)
            #pragma unroll
            for (int n = 0; n < 4; ++n)
                *(f32x4*)(mbase + swzM(n * 16 + i, h * 64 + g * 16)) = oacc[h][n];
        if (g == 0) { lbase[tg * 32 + i] = l0; lbase[tg * 32 + 16 + i] = l1; }
    }
    __syncthreads();
    if (half == 0) {
        #pragma unroll
        for (int h = 0; h < 2; ++h)
            #pragma unroll
            for (int n = 0; n < 4; ++n)
                oacc[h][n] += *(const f32x4*)(mbase + swzM(n * 16 + i, h * 64 + g * 16));
        l0 += lbase[tg * 32 + i];
        l1 += lbase[tg * 32 + 16 + i];
    }
    __syncthreads();   // merge reads done before Obuf overwrites [0,32K)
    if (half == 0) {
        #pragma unroll
        for (int h = 0; h < 2; ++h) {
            float invl = 1.0f / (h ? l1 : l0);
            #pragma unroll
            for (int reg = 0; reg < 4; ++reg) {
                float inv_r = __shfl(invl, g * 4 + reg);
                int t_loc = tg * 32 + h * 16 + g * 4 + reg;
                #pragma unroll
                for (int n = 0; n < 4; ++n) {
                    int c = n * 16 + i;
                    *(float*)(lds + swzO(c, t_loc * 4)) = oacc[h][n][reg] * inv_r;
                }
            }
        }
    }
    __syncthreads();
    #pragma unroll
    for (int it = 0; it < 4; ++it) {
        int idx = it * 512 + tid;
        int c   = idx >> 5;
        int seg = idx & 31;
        float4 u = *(const float4*)(lds + swzO(c, seg * 16));
        *(float4*)(out + (size_t)(bh * 64 + c) * T_LEN + t0 + seg * 4) = u;
    }
}

// ---------------- tiny correct fallback (ws too small; r3-verified) ---------
__global__ __launch_bounds__(256)
void simple_attn(const float* __restrict__ qkv, float* __restrict__ out) {
    const int wave = threadIdx.x >> 6;
    const int lane = threadIdx.x & 63;
    const int t  = blockIdx.x * 4 + wave;
    const int bh = blockIdx.y;
    const float* qp = qkv + (size_t)bh * 192 * T_LEN;
    const float* kp = qp + (size_t)64  * T_LEN;
    const float* vp = qp + (size_t)128 * T_LEN;
    const float qc = qp[(size_t)lane * T_LEN + t] * 0.125f;
    float m = -1e30f, l = 0.f, o = 0.f;
    for (int s = 0; s < T_LEN; ++s) {
        float prod = qc * kp[(size_t)lane * T_LEN + s];
        #pragma unroll
        for (int d = 1; d < 64; d <<= 1) prod += __shfl_xor(prod, d);
        const float nm   = fmaxf(m, prod);
        const float corr = __expf(m - nm);
        const float p    = __expf(prod - nm);
        l = l * corr + p;
        o = o * corr + p * vp[(size_t)lane * T_LEN + s];
        m = nm;
    }
    out[(size_t)(bh * 64 + lane) * T_LEN + t] = o / l;
}

extern "C" void kernel_launch(void* const* d_in, const int* in_sizes, int n_in,
                              void* d_out, int out_size, void* d_ws, size_t ws_size,
                              hipStream_t stream) {
    const float* qkv = (const float*)d_in[0];
    float* out = (float*)d_out;
    const size_t pan_bytes = (size_t)16 * 64 * 8192;   // 8.39 MB per panel set
    if (ws_size >= 2 * pan_bytes) {
        char* kpan = (char*)d_ws;
        char* vpan = kpan + pan_bytes;
        qkv_prepass<<<dim3(64, 16), 256, 0, stream>>>(qkv, kpan, vpan);
        qkv_attn_hyb<<<dim3(512), 512, 0, stream>>>(qkv, out, kpan, vpan);
    } else {
        simple_attn<<<dim3(T_LEN / 4, 16), 256, 0, stream>>>(qkv, out);
    }
}

// Round 22
// 89.087 us; speedup vs baseline: 1.5213x; 1.5213x over previous
//
#include <hip/hip_runtime.h>
#include <hip/hip_bf16.h>

typedef __bf16 bf16x8 __attribute__((ext_vector_type(8)));
typedef __bf16 bf16x4 __attribute__((ext_vector_type(4)));
typedef __bf16 bf16x2 __attribute__((ext_vector_type(2)));
typedef float  f32x4  __attribute__((ext_vector_type(4)));

#define T_LEN 4096
#define QBLK  128
#define NIT   32          // 32 superblocks x 128 s

__device__ __forceinline__ int swz(int row, int colByte) {
    return row * 128 + (colByte ^ (((row ^ (row >> 2)) & 7) << 4));
}
__device__ __forceinline__ int swzM(int row, int colByte) {   // merge buf [c][t] f32
    return row * 128 + (colByte ^ ((row & 7) << 4));
}
__device__ __forceinline__ int swzO(int row, int colByte) {   // epilogue f32 [c][128t]
    return row * 512 + (colByte ^ ((row & 7) << 5));
}

// Q pre-scale: 1/8 (QK scale) x log2(e); no-max exp2 softmax (r9-verified).
#define QSCALE 0.18033688011112042f

#if __has_builtin(__builtin_amdgcn_exp2f)
#define EXP2(x) __builtin_amdgcn_exp2f(x)
#else
__device__ __forceinline__ float EXP2(float x) {
    float r; asm("v_exp_f32 %0, %1" : "=v"(r) : "v"(x)); return r;
}
#endif

__device__ __forceinline__ void glds16(const void* g, void* l) {
    __builtin_amdgcn_global_load_lds(
        (const __attribute__((address_space(1))) void*)g,
        (__attribute__((address_space(3))) void*)l, 16, 0, 0);
}

// ---------------- prepass: K,V -> bf16 swizzled LDS images in d_ws ----------
__global__ __launch_bounds__(256)
void qkv_prepass(const float* __restrict__ qkv, char* __restrict__ kpan,
                 char* __restrict__ vpan) {
    const int tile = blockIdx.x;    // 0..63
    const int bh   = blockIdx.y;    // 0..15
    const float* kp = qkv + ((size_t)bh * 192 + 64)  * T_LEN + tile * 64;
    const float* vp = qkv + ((size_t)bh * 192 + 128) * T_LEN + tile * 64;
    char* kout = kpan + (size_t)(bh * 64 + tile) * 8192;
    char* vout = vpan + (size_t)(bh * 64 + tile) * 8192;

    const int t  = threadIdx.x;
    const int s  = t & 63;
    const int o4 = t >> 6;          // 0..3
    #pragma unroll
    for (int oo = 0; oo < 2; ++oo) {
        const int oct = o4 + oo * 4;                 // c-octet 0..7
        bf16x8 v;
        #pragma unroll
        for (int j = 0; j < 8; ++j)
            v[j] = (__bf16)kp[(size_t)(oct * 8 + j) * T_LEN + s];
        *(bf16x8*)(kout + swz(s, oct * 16)) = v;
    }
    const int c = t & 63;
    #pragma unroll
    for (int p = 0; p < 4; ++p) {
        const int u = o4 * 4 + p;                    // s-chunk 0..15
        float4 f = *(const float4*)(vp + (size_t)c * T_LEN + u * 4);
        const int up = (u & 8) | ((u & 3) << 1) | ((u >> 2) & 1);
        bf16x4 hv;
        hv[0] = (__bf16)f.x; hv[1] = (__bf16)f.y;
        hv[2] = (__bf16)f.z; hv[3] = (__bf16)f.w;
        *(bf16x4*)(vout + swz(c, up * 8)) = hv;
    }
}

// ---------------- main: r18 champion (superblock dbuf + phase grouping) -----
// 8 waves = 4 t-groups x 2 s-halves; 2 blocks/CU (4 waves/SIMD — r17 lesson:
// 8/SIMD infeasible; r19 counted-vmcnt null; r20 no-LDS regress; r21 hybrid
// spills). Superblock (2x64s tiles) per barrier; phases grouped: {S: K-reads
// + 32 MFMA} {exp: 32 exp2+pack} {PV: V-reads + 32 MFMA}; setprio (T5)
// around MFMA clusters.
// LDS map: [0,16K) Qs (dead after qreg; lbase + Obuf reuse) |
//          [16K,48K) Ks dbuf 2x16K (mbase reuse post-loop) | [48K,80K) Vs dbuf.
__global__ __launch_bounds__(512, 4)
void qkv_attn_glds(const float* __restrict__ qkv, float* __restrict__ out,
                   const char* __restrict__ kpan, const char* __restrict__ vpan) {
    __shared__ __align__(16) char lds[81920];

    const int fid   = (blockIdx.x & 7) * 64 + (blockIdx.x >> 3);   // T1 swizzle
    const int bh    = fid >> 5;
    const int ttile = fid & 31;
    const float* qp = qkv + (size_t)bh * 192 * T_LEN;
    const char* kpb = kpan + (size_t)bh * 64 * 8192;
    const char* vpb = vpan + (size_t)bh * 64 * 8192;
    const int t0 = ttile * QBLK;

    const int tid  = threadIdx.x;
    const int wave = tid >> 6, lane = tid & 63;
    const int g = lane >> 4, i = lane & 15;
    const int tg = wave >> 1, half = wave & 1;   // t-group (32 rows), s-half

    // ---- prologue: async-stage superblock 0 (tiles 0,1) ----
    glds16(kpb + tid * 16,        lds + 16384 + wave * 1024);
    glds16(kpb + 8192 + tid * 16, lds + 16384 + 8192 + wave * 1024);
    glds16(vpb + tid * 16,        lds + 49152 + wave * 1024);
    glds16(vpb + 8192 + tid * 16, lds + 49152 + 8192 + wave * 1024);

    // ---- stage Q^T x QSCALE : [128 t][64 c] ----
    {
        const int tq  = (tid & 31) * 4;
        const int cp8 = tid >> 5;
        #pragma unroll
        for (int hh = 0; hh < 2; ++hh) {
            const int cpair = cp8 + hh * 16;
            const float* base = qp + (size_t)(cpair * 2) * T_LEN + t0 + tq;
            float4 lo = *(const float4*)(base);
            float4 hi = *(const float4*)(base + T_LEN);
            bf16x2 v;
            v[0] = (__bf16)(lo.x * QSCALE); v[1] = (__bf16)(hi.x * QSCALE);
            *(bf16x2*)(lds + swz(tq + 0, cpair * 4)) = v;
            v[0] = (__bf16)(lo.y * QSCALE); v[1] = (__bf16)(hi.y * QSCALE);
            *(bf16x2*)(lds + swz(tq + 1, cpair * 4)) = v;
            v[0] = (__bf16)(lo.z * QSCALE); v[1] = (__bf16)(hi.z * QSCALE);
            *(bf16x2*)(lds + swz(tq + 2, cpair * 4)) = v;
            v[0] = (__bf16)(lo.w * QSCALE); v[1] = (__bf16)(hi.w * QSCALE);
            *(bf16x2*)(lds + swz(tq + 3, cpair * 4)) = v;
        }
    }
    __syncthreads();   // Q staged + superblock 0 drained
    bf16x8 qreg[2][2];   // [t-half][kk], loop-invariant; Qs LDS dead after
    #pragma unroll
    for (int h = 0; h < 2; ++h)
        #pragma unroll
        for (int kk = 0; kk < 2; ++kk)
            qreg[h][kk] = *(const bf16x8*)(lds + swz(tg * 32 + h * 16 + i, kk * 64 + g * 16));

    f32x4 oacc[2][4];
    #pragma unroll
    for (int h = 0; h < 2; ++h)
        #pragma unroll
        for (int n = 0; n < 4; ++n) oacc[h][n] = (f32x4){0.f, 0.f, 0.f, 0.f};
    float l0 = 0.f, l1 = 0.f;   // lane-local partials; shfl-reduced post-loop

    for (int it = 0; it < NIT; ++it) {
        // ---- async-issue next superblock ----
        if (it + 1 < NIT) {
            const size_t off = (size_t)(2 * it + 2) * 8192;
            const int b = (it + 1) & 1;
            glds16(kpb + off + tid * 16,        lds + 16384 + b * 16384 + wave * 1024);
            glds16(kpb + off + 8192 + tid * 16, lds + 16384 + b * 16384 + 8192 + wave * 1024);
            glds16(vpb + off + tid * 16,        lds + 49152 + b * 16384 + wave * 1024);
            glds16(vpb + off + 8192 + tid * 16, lds + 49152 + b * 16384 + 8192 + wave * 1024);
        }
        char* KsB = lds + 16384 + (it & 1) * 16384;
        char* VsB = lds + 49152 + (it & 1) * 16384;

        // ---- S phase: both chains' K-frags + 32 S-MFMAs ----
        f32x4 sacc[2][2][2];   // [ta][t-half][mt]
        #pragma unroll
        for (int ta = 0; ta < 2; ++ta)
            #pragma unroll
            for (int h = 0; h < 2; ++h)
                #pragma unroll
                for (int mt = 0; mt < 2; ++mt) sacc[ta][h][mt] = (f32x4){0.f, 0.f, 0.f, 0.f};
        __builtin_amdgcn_s_setprio(1);
        #pragma unroll
        for (int ta = 0; ta < 2; ++ta)
            #pragma unroll
            for (int kk = 0; kk < 2; ++kk)
                #pragma unroll
                for (int mt = 0; mt < 2; ++mt) {
                    bf16x8 kf = *(const bf16x8*)(KsB + ta * 8192 + swz(half * 32 + mt * 16 + i, kk * 64 + g * 16));
                    sacc[ta][0][mt] = __builtin_amdgcn_mfma_f32_16x16x32_bf16(kf, qreg[0][kk], sacc[ta][0][mt], 0, 0, 0);
                    sacc[ta][1][mt] = __builtin_amdgcn_mfma_f32_16x16x32_bf16(kf, qreg[1][kk], sacc[ta][1][mt], 0, 0, 0);
                }
        __builtin_amdgcn_s_setprio(0);

        // ---- exp phase: 32 exp2 + packs ----
        bf16x8 pa[2][2];   // [ta][t-half]
        #pragma unroll
        for (int ta = 0; ta < 2; ++ta)
            #pragma unroll
            for (int r = 0; r < 4; ++r) {
                float a0 = EXP2(sacc[ta][0][0][r]);
                float a1 = EXP2(sacc[ta][0][1][r]);
                l0 += a0 + a1;
                pa[ta][0][r] = (__bf16)a0; pa[ta][0][4 + r] = (__bf16)a1;
                float b0 = EXP2(sacc[ta][1][0][r]);
                float b1 = EXP2(sacc[ta][1][1][r]);
                l1 += b0 + b1;
                pa[ta][1][r] = (__bf16)b0; pa[ta][1][4 + r] = (__bf16)b1;
            }

        // ---- PV phase: 8 V-frags + 32 PV-MFMAs ----
        __builtin_amdgcn_s_setprio(1);
        #pragma unroll
        for (int ta = 0; ta < 2; ++ta)
            #pragma unroll
            for (int n = 0; n < 4; ++n) {
                bf16x8 bv = *(const bf16x8*)(VsB + ta * 8192 + swz(n * 16 + i, half * 64 + g * 16));
                oacc[0][n] = __builtin_amdgcn_mfma_f32_16x16x32_bf16(pa[ta][0], bv, oacc[0][n], 0, 0, 0);
                oacc[1][n] = __builtin_amdgcn_mfma_f32_16x16x32_bf16(pa[ta][1], bv, oacc[1][n], 0, 0, 0);
            }
        __builtin_amdgcn_s_setprio(0);
        __syncthreads();   // next bufs ready (drains glds); reads fenced
    }
    l0 += __shfl_xor(l0, 16); l0 += __shfl_xor(l0, 32);
    l1 += __shfl_xor(l1, 16); l1 += __shfl_xor(l1, 32);

    // ---- merge s-halves (additive), then epilogue ----
    char* mbase = lds + 16384 + tg * 8192;   // [64 c][32 t] f32, swzM (K dbuf dead)
    float* lbase = (float*)(lds);            // Qs region dead
    if (half == 1) {
        #pragma unroll
        for (int h = 0; h < 2; ++h)
            #pragma unroll
            for (int n = 0; n < 4; ++n)
                *(f32x4*)(mbase + swzM(n * 16 + i, h * 64 + g * 16)) = oacc[h][n];
        if (g == 0) { lbase[tg * 32 + i] = l0; lbase[tg * 32 + 16 + i] = l1; }
    }
    __syncthreads();
    if (half == 0) {
        #pragma unroll
        for (int h = 0; h < 2; ++h)
            #pragma unroll
            for (int n = 0; n < 4; ++n)
                oacc[h][n] += *(const f32x4*)(mbase + swzM(n * 16 + i, h * 64 + g * 16));
        l0 += lbase[tg * 32 + i];
        l1 += lbase[tg * 32 + 16 + i];
    }
    __syncthreads();   // merge reads done before Obuf overwrites [0,32K)
    if (half == 0) {
        #pragma unroll
        for (int h = 0; h < 2; ++h) {
            float invl = 1.0f / (h ? l1 : l0);
            #pragma unroll
            for (int reg = 0; reg < 4; ++reg) {
                float inv_r = __shfl(invl, g * 4 + reg);
                int t_loc = tg * 32 + h * 16 + g * 4 + reg;
                #pragma unroll
                for (int n = 0; n < 4; ++n) {
                    int c = n * 16 + i;
                    *(float*)(lds + swzO(c, t_loc * 4)) = oacc[h][n][reg] * inv_r;
                }
            }
        }
    }
    __syncthreads();
    #pragma unroll
    for (int it = 0; it < 4; ++it) {
        int idx = it * 512 + tid;
        int c   = idx >> 5;
        int seg = idx & 31;
        float4 u = *(const float4*)(lds + swzO(c, seg * 16));
        *(float4*)(out + (size_t)(bh * 64 + c) * T_LEN + t0 + seg * 4) = u;
    }
}

// ---------------- tiny correct fallback (ws too small; r3-verified) ---------
__global__ __launch_bounds__(256)
void simple_attn(const float* __restrict__ qkv, float* __restrict__ out) {
    const int wave = threadIdx.x >> 6;
    const int lane = threadIdx.x & 63;
    const int t  = blockIdx.x * 4 + wave;
    const int bh = blockIdx.y;
    const float* qp = qkv + (size_t)bh * 192 * T_LEN;
    const float* kp = qp + (size_t)64  * T_LEN;
    const float* vp = qp + (size_t)128 * T_LEN;
    const float qc = qp[(size_t)lane * T_LEN + t] * 0.125f;
    float m = -1e30f, l = 0.f, o = 0.f;
    for (int s = 0; s < T_LEN; ++s) {
        float prod = qc * kp[(size_t)lane * T_LEN + s];
        #pragma unroll
        for (int d = 1; d < 64; d <<= 1) prod += __shfl_xor(prod, d);
        const float nm   = fmaxf(m, prod);
        const float corr = __expf(m - nm);
        const float p    = __expf(prod - nm);
        l = l * corr + p;
        o = o * corr + p * vp[(size_t)lane * T_LEN + s];
        m = nm;
    }
    out[(size_t)(bh * 64 + lane) * T_LEN + t] = o / l;
}

extern "C" void kernel_launch(void* const* d_in, const int* in_sizes, int n_in,
                              void* d_out, int out_size, void* d_ws, size_t ws_size,
                              hipStream_t stream) {
    const float* qkv = (const float*)d_in[0];
    float* out = (float*)d_out;
    const size_t pan_bytes = (size_t)16 * 64 * 8192;   // 8.39 MB per panel set
    if (ws_size >= 2 * pan_bytes) {
        char* kpan = (char*)d_ws;
        char* vpan = kpan + pan_bytes;
        qkv_prepass<<<dim3(64, 16), 256, 0, stream>>>(qkv, kpan, vpan);
        qkv_attn_glds<<<dim3(512), 512, 0, stream>>>(qkv, out, kpan, vpan);
    } else {
        simple_attn<<<dim3(T_LEN / 4, 16), 256, 0, stream>>>(qkv, out);
    }
}